// Round 1
// baseline (743.668 us; speedup 1.0000x reference)
//
#include <hip/hip_runtime.h>
#include <math.h>

// Problem constants (fixed by setup_inputs)
#define NB   4
#define NSEQ 2048
#define CIN  128
#define COUT 128
#define NH   8
#define DHD  16      // dims per head
#define EDIM 48      // DHD * 3
static constexpr float kBiasEps = 1e-6f;

// ---------------------------------------------------------------------------
// Transpose the four 128x128 weight matrices: Wt[i][o] = W[o][i]
// grid (64, 4), block 256
__global__ __launch_bounds__(256) void transpose_w(
    const float* __restrict__ w0, const float* __restrict__ w1,
    const float* __restrict__ w2, const float* __restrict__ w3,
    float* __restrict__ wt)
{
    const float* src;
    switch (blockIdx.y) {
        case 0:  src = w0; break;
        case 1:  src = w1; break;
        case 2:  src = w2; break;
        default: src = w3; break;
    }
    float* dst = wt + (size_t)blockIdx.y * (CIN * COUT);
    const int idx = blockIdx.x * 256 + threadIdx.x;   // [0, 16384)
    const int i = idx >> 7;
    const int o = idx & 127;
    dst[idx] = src[o * CIN + i];
}

// ---------------------------------------------------------------------------
// Fused projection + VN bias-norm + head split.
// y[b,o,c,n] = sum_i W[o,i] x[b,n,i,c];  out = y*(1 + b[o]/(||y||_c + eps))
// dst[b,h,n,(o%16)*3+c], h = o/16.
// grid (NB*NSEQ/8, 3), block 256. thread: nl = t>>5 (8 rows), o0 = (t&31)*4.
__global__ __launch_bounds__(256) void vn_proj(
    const float* __restrict__ qin, const float* __restrict__ vin,
    const float* __restrict__ wt_all,
    const float* __restrict__ bq, const float* __restrict__ bk,
    const float* __restrict__ bv,
    float* __restrict__ qh, float* __restrict__ kh, float* __restrict__ vh)
{
    const float* x; const float* wt; const float* bias; float* dst;
    switch (blockIdx.y) {
        case 0:  x = qin; wt = wt_all;               bias = bq; dst = qh; break;
        case 1:  x = vin; wt = wt_all + CIN * COUT;  bias = bk; dst = kh; break;
        default: x = vin; wt = wt_all + 2*CIN*COUT;  bias = bv; dst = vh; break;
    }
    const int t  = threadIdx.x;
    const int nl = t >> 5;
    const int o0 = (t & 31) << 2;
    const long bn = (long)blockIdx.x * 8 + nl;      // b*NSEQ + n
    const int b = (int)(bn >> 11);
    const int n = (int)(bn & (NSEQ - 1));
    const float* xr = x + bn * (CIN * 3);

    float a[4][3] = {};
    for (int i = 0; i < CIN; ++i) {
        const float4 w = *(const float4*)(wt + (size_t)i * COUT + o0);
        const float wv[4] = { w.x, w.y, w.z, w.w };
        const float xv[3] = { xr[i*3+0], xr[i*3+1], xr[i*3+2] };
        #pragma unroll
        for (int j = 0; j < 4; ++j)
            #pragma unroll
            for (int c = 0; c < 3; ++c)
                a[j][c] = fmaf(wv[j], xv[c], a[j][c]);
    }
    #pragma unroll
    for (int j = 0; j < 4; ++j) {
        const int o = o0 + j;
        const float nrm = sqrtf(a[j][0]*a[j][0] + a[j][1]*a[j][1] + a[j][2]*a[j][2]);
        const float f = 1.0f + bias[o] / (nrm + kBiasEps);
        float* dp = dst + (((size_t)b * NH + (o >> 4)) * NSEQ + n) * EDIM + (o & 15) * 3;
        dp[0] = a[j][0] * f;
        dp[1] = a[j][1] * f;
        dp[2] = a[j][2] * f;
    }
}

// ---------------------------------------------------------------------------
// Flash-style f32 attention. 4 lanes per q row (12 dims each).
// grid (NSEQ/64, NH, NB), block 256: 64 q rows per block.
__global__ __launch_bounds__(256) void vn_attn(
    const float* __restrict__ qh, const float* __restrict__ kh,
    const float* __restrict__ vh, float* __restrict__ xo)
{
    __shared__ __align__(16) float ks[64 * EDIM];
    __shared__ __align__(16) float vs[64 * EDIM];

    const int t  = threadIdx.x;
    const int qr = t >> 2;
    const int e0 = (t & 3) * 12;
    const int bh = blockIdx.z * NH + blockIdx.y;
    const long q_row = (long)bh * NSEQ + blockIdx.x * 64 + qr;

    const float scale = 0.14433756729740643f;  // 48^-0.5
    float q[12];
    {
        const float* qp = qh + q_row * EDIM + e0;
        const float4 a0 = *(const float4*)(qp);
        const float4 a1 = *(const float4*)(qp + 4);
        const float4 a2 = *(const float4*)(qp + 8);
        q[0]=a0.x*scale; q[1]=a0.y*scale; q[2] =a0.z*scale; q[3] =a0.w*scale;
        q[4]=a1.x*scale; q[5]=a1.y*scale; q[6] =a1.z*scale; q[7] =a1.w*scale;
        q[8]=a2.x*scale; q[9]=a2.y*scale; q[10]=a2.z*scale; q[11]=a2.w*scale;
    }
    float acc[12] = {};
    float m = -1e30f, l = 0.0f;

    const float* khb = kh + (long)bh * NSEQ * EDIM;
    const float* vhb = vh + (long)bh * NSEQ * EDIM;

    for (int kt = 0; kt < NSEQ; kt += 64) {
        __syncthreads();
        {
            const float4* ksrc = (const float4*)(khb + (long)kt * EDIM);
            const float4* vsrc = (const float4*)(vhb + (long)kt * EDIM);
            #pragma unroll
            for (int r = 0; r < 3; ++r) {
                ((float4*)ks)[t + r*256] = ksrc[t + r*256];
                ((float4*)vs)[t + r*256] = vsrc[t + r*256];
            }
        }
        __syncthreads();
        for (int kk = 0; kk < 64; ++kk) {
            const float* kp = ks + kk * EDIM + e0;
            const float4 k0 = *(const float4*)(kp);
            const float4 k1 = *(const float4*)(kp + 4);
            const float4 k2 = *(const float4*)(kp + 8);
            float s = fmaf(q[0], k0.x, fmaf(q[1], k0.y, fmaf(q[2],  k0.z, q[3] * k0.w)))
                    + fmaf(q[4], k1.x, fmaf(q[5], k1.y, fmaf(q[6],  k1.z, q[7] * k1.w)))
                    + fmaf(q[8], k2.x, fmaf(q[9], k2.y, fmaf(q[10], k2.z, q[11]* k2.w)));
            s += __shfl_xor(s, 1, 4);
            s += __shfl_xor(s, 2, 4);
            if (__any(s > m + 8.0f)) {       // defer-max: rescale only on big jumps
                const float mn = fmaxf(m, s);
                const float alpha = __expf(m - mn);
                l *= alpha;
                #pragma unroll
                for (int j = 0; j < 12; ++j) acc[j] *= alpha;
                m = mn;
            }
            const float p = __expf(s - m);
            l += p;
            const float* vp = vs + kk * EDIM + e0;
            const float4 v0 = *(const float4*)(vp);
            const float4 v1 = *(const float4*)(vp + 4);
            const float4 v2 = *(const float4*)(vp + 8);
            acc[0] = fmaf(p, v0.x, acc[0]); acc[1] = fmaf(p, v0.y, acc[1]);
            acc[2] = fmaf(p, v0.z, acc[2]); acc[3] = fmaf(p, v0.w, acc[3]);
            acc[4] = fmaf(p, v1.x, acc[4]); acc[5] = fmaf(p, v1.y, acc[5]);
            acc[6] = fmaf(p, v1.z, acc[6]); acc[7] = fmaf(p, v1.w, acc[7]);
            acc[8] = fmaf(p, v2.x, acc[8]); acc[9] = fmaf(p, v2.y, acc[9]);
            acc[10]= fmaf(p, v2.z, acc[10]);acc[11]= fmaf(p, v2.w, acc[11]);
        }
    }

    const float inv = 1.0f / l;
    float* xp = xo + q_row * EDIM + e0;
    *(float4*)(xp)     = make_float4(acc[0]*inv, acc[1]*inv, acc[2]*inv,  acc[3]*inv);
    *(float4*)(xp + 4) = make_float4(acc[4]*inv, acc[5]*inv, acc[6]*inv,  acc[7]*inv);
    *(float4*)(xp + 8) = make_float4(acc[8]*inv, acc[9]*inv, acc[10]*inv, acc[11]*inv);
}

// ---------------------------------------------------------------------------
// Output projection + VN bias-norm, gathering from x[b,h,n,e] and writing
// out[b,n,o,c]. grid (NB*NSEQ/8), block 256.
__global__ __launch_bounds__(256) void vn_oproj(
    const float* __restrict__ xb,   // [NB,NH,NSEQ,EDIM]
    const float* __restrict__ wt,   // Wp^T [CIN][COUT]
    const float* __restrict__ bias,
    float* __restrict__ out)        // [NB,NSEQ,COUT,3]
{
    const int t  = threadIdx.x;
    const int nl = t >> 5;
    const int o0 = (t & 31) << 2;
    const long bn = (long)blockIdx.x * 8 + nl;
    const int b = (int)(bn >> 11);
    const int n = (int)(bn & (NSEQ - 1));
    const float* xbase = xb + ((size_t)b * NH * NSEQ + n) * EDIM;

    float a[4][3] = {};
    for (int i = 0; i < CIN; ++i) {
        const float4 w = *(const float4*)(wt + (size_t)i * COUT + o0);
        const float wv[4] = { w.x, w.y, w.z, w.w };
        const float* xp = xbase + (size_t)(i >> 4) * NSEQ * EDIM + (i & 15) * 3;
        const float xv[3] = { xp[0], xp[1], xp[2] };
        #pragma unroll
        for (int j = 0; j < 4; ++j)
            #pragma unroll
            for (int c = 0; c < 3; ++c)
                a[j][c] = fmaf(wv[j], xv[c], a[j][c]);
    }
    #pragma unroll
    for (int j = 0; j < 4; ++j) {
        const int o = o0 + j;
        const float nrm = sqrtf(a[j][0]*a[j][0] + a[j][1]*a[j][1] + a[j][2]*a[j][2]);
        const float f = 1.0f + bias[o] / (nrm + kBiasEps);
        float* dp = out + ((size_t)bn * COUT + o) * 3;
        dp[0] = a[j][0] * f;
        dp[1] = a[j][1] * f;
        dp[2] = a[j][2] * f;
    }
}

// ---------------------------------------------------------------------------
extern "C" void kernel_launch(void* const* d_in, const int* in_sizes, int n_in,
                              void* d_out, int out_size, void* d_ws, size_t ws_size,
                              hipStream_t stream)
{
    const float* q  = (const float*)d_in[0];
    const float* v  = (const float*)d_in[1];
    const float* Wq = (const float*)d_in[2];
    const float* bq = (const float*)d_in[3];
    const float* Wk = (const float*)d_in[4];
    const float* bk = (const float*)d_in[5];
    const float* Wv = (const float*)d_in[6];
    const float* bv = (const float*)d_in[7];
    const float* Wp = (const float*)d_in[8];
    const float* bp = (const float*)d_in[9];
    float* out = (float*)d_out;
    float* ws  = (float*)d_ws;

    const size_t WT_FLOATS  = (size_t)4 * CIN * COUT;          // 65536
    const size_t BUF_FLOATS = (size_t)NB * NH * NSEQ * EDIM;   // 3145728

    float* wt = ws;
    float* qh = ws + WT_FLOATS;
    float* kh = qh + BUF_FLOATS;
    float* vh = kh + BUF_FLOATS;
    float* xb = vh + BUF_FLOATS;

    transpose_w<<<dim3(64, 4), 256, 0, stream>>>(Wq, Wk, Wv, Wp, wt);
    vn_proj<<<dim3(NB * NSEQ / 8, 3), 256, 0, stream>>>(
        q, v, wt, bq, bk, bv, qh, kh, vh);
    vn_attn<<<dim3(NSEQ / 64, NH, NB), 256, 0, stream>>>(qh, kh, vh, xb);
    vn_oproj<<<dim3(NB * NSEQ / 8), 256, 0, stream>>>(
        xb, wt + 3 * (size_t)CIN * COUT, bp, out);
}

// Round 3
// 300.088 us; speedup vs baseline: 2.4782x; 2.4782x over previous
//
#include <hip/hip_runtime.h>
#include <hip/hip_bf16.h>
#include <math.h>

// Problem constants (fixed by setup_inputs)
#define NB   4
#define NSEQ 2048
#define CIN  128
#define COUT 128
#define NH   8
#define EDIM 48      // head dim*3
static constexpr float kBiasEps = 1e-6f;
// fold 48^-0.5 and log2(e) into Q so softmax uses exp2 directly
static constexpr float kQScale = (float)(0.14433756729740643 * 1.4426950408889634);

typedef __attribute__((ext_vector_type(8)))  short bf16x8;
typedef __attribute__((ext_vector_type(16))) float f32x16;
typedef __attribute__((ext_vector_type(4)))  unsigned int u32x4;

__device__ inline unsigned short f2bf(float f) {
    __hip_bfloat16 h = __float2bfloat16(f);
    return *reinterpret_cast<unsigned short*>(&h);
}
__device__ inline float bf2f(unsigned short u) {
    unsigned int x = (unsigned int)u << 16;
    return __uint_as_float(x);
}
__device__ inline unsigned int cvt_pk_bf16(float lo, float hi) {
    unsigned int r;
    asm("v_cvt_pk_bf16_f32 %0, %1, %2" : "=v"(r) : "v"(lo), "v"(hi));
    return r;
}

// ---------------------------------------------------------------------------
// Transpose the four 128x128 weight matrices: Wt[i][o] = W[o][i]
__global__ __launch_bounds__(256) void transpose_w(
    const float* __restrict__ w0, const float* __restrict__ w1,
    const float* __restrict__ w2, const float* __restrict__ w3,
    float* __restrict__ wt)
{
    const float* src;
    switch (blockIdx.y) {
        case 0:  src = w0; break;
        case 1:  src = w1; break;
        case 2:  src = w2; break;
        default: src = w3; break;
    }
    float* dst = wt + (size_t)blockIdx.y * (CIN * COUT);
    const int idx = blockIdx.x * 256 + threadIdx.x;
    const int i = idx >> 7;
    const int o = idx & 127;
    dst[idx] = src[o * CIN + i];
}

// ---------------------------------------------------------------------------
// Fused projection + VN bias-norm + head split, f32 math, split-bf16 outputs.
// Q -> qh_hi/lo[bh][n][48] (scaled), K -> kh_hi/lo[bh][n][48],
// V -> vt_hi/lo[bh][e(64)][n]  (transposed for the PV MFMA B-operand).
__global__ __launch_bounds__(256) void vn_proj(
    const float* __restrict__ qin, const float* __restrict__ vin,
    const float* __restrict__ wt_all,
    const float* __restrict__ bq, const float* __restrict__ bk,
    const float* __restrict__ bv,
    unsigned short* __restrict__ qh_hi, unsigned short* __restrict__ qh_lo,
    unsigned short* __restrict__ kh_hi, unsigned short* __restrict__ kh_lo,
    unsigned short* __restrict__ vt_hi, unsigned short* __restrict__ vt_lo)
{
    const float* x; const float* wt; const float* bias;
    switch (blockIdx.y) {
        case 0:  x = qin; wt = wt_all;               bias = bq; break;
        case 1:  x = vin; wt = wt_all + CIN * COUT;  bias = bk; break;
        default: x = vin; wt = wt_all + 2*CIN*COUT;  bias = bv; break;
    }
    const int t  = threadIdx.x;
    const int nl = t >> 5;
    const int o0 = (t & 31) << 2;
    const long bn = (long)blockIdx.x * 8 + nl;      // b*NSEQ + n
    const int b = (int)(bn >> 11);
    const int n = (int)(bn & (NSEQ - 1));
    const float* xr = x + bn * (CIN * 3);

    float a[4][3] = {};
    for (int i = 0; i < CIN; ++i) {
        const float4 w = *(const float4*)(wt + (size_t)i * COUT + o0);
        const float wv[4] = { w.x, w.y, w.z, w.w };
        const float xv[3] = { xr[i*3+0], xr[i*3+1], xr[i*3+2] };
        #pragma unroll
        for (int j = 0; j < 4; ++j)
            #pragma unroll
            for (int c = 0; c < 3; ++c)
                a[j][c] = fmaf(wv[j], xv[c], a[j][c]);
    }
    #pragma unroll
    for (int j = 0; j < 4; ++j) {
        const int o = o0 + j;
        const float nrm = sqrtf(a[j][0]*a[j][0] + a[j][1]*a[j][1] + a[j][2]*a[j][2]);
        float f = 1.0f + bias[o] / (nrm + kBiasEps);
        const int h = o >> 4;
        const int e = (o & 15) * 3;
        const size_t bh = (size_t)b * NH + h;
        if (blockIdx.y == 0) f *= kQScale;
        float y0 = a[j][0]*f, y1 = a[j][1]*f, y2 = a[j][2]*f;
        unsigned short h0 = f2bf(y0), h1 = f2bf(y1), h2 = f2bf(y2);
        unsigned short l0 = f2bf(y0 - bf2f(h0));
        unsigned short l1 = f2bf(y1 - bf2f(h1));
        unsigned short l2 = f2bf(y2 - bf2f(h2));
        if (blockIdx.y == 0) {
            const size_t off = (bh * NSEQ + n) * EDIM + e;
            qh_hi[off] = h0; qh_hi[off+1] = h1; qh_hi[off+2] = h2;
            qh_lo[off] = l0; qh_lo[off+1] = l1; qh_lo[off+2] = l2;
        } else if (blockIdx.y == 1) {
            const size_t off = (bh * NSEQ + n) * EDIM + e;
            kh_hi[off] = h0; kh_hi[off+1] = h1; kh_hi[off+2] = h2;
            kh_lo[off] = l0; kh_lo[off+1] = l1; kh_lo[off+2] = l2;
        } else {
            const size_t off = (bh * 64 + e) * NSEQ + n;
            vt_hi[off] = h0; vt_hi[off+NSEQ] = h1; vt_hi[off+2*NSEQ] = h2;
            vt_lo[off] = l0; vt_lo[off+NSEQ] = l1; vt_lo[off+2*NSEQ] = l2;
        }
    }
}

// ---------------------------------------------------------------------------
// MFMA flash attention with split-bf16 operands (effective fp32 precision).
// Wave owns 32 q rows; block = 4 waves = 128 q rows.
// S^T = K.Q^T (swapped operands -> q is lane-local).
// grid (NSEQ/128, NH, NB), block 256.
__global__ __launch_bounds__(256) void vn_attn_mfma(
    const unsigned short* __restrict__ qh_hi, const unsigned short* __restrict__ qh_lo,
    const unsigned short* __restrict__ kh_hi, const unsigned short* __restrict__ kh_lo,
    const unsigned short* __restrict__ vt_hi, const unsigned short* __restrict__ vt_lo,
    float* __restrict__ xb)
{
    const int lane = threadIdx.x & 63;
    const int wid  = threadIdx.x >> 6;
    const int lq   = lane & 31;
    const int half = lane >> 5;
    const int bh   = blockIdx.z * NH + blockIdx.y;
    const int q0   = blockIdx.x * 128 + wid * 32;

    // Q B-fragments (B[k=e][n=q]: lane -> q=lq, e = 16*i + 8*half + j)
    const size_t qoff = ((size_t)bh * NSEQ + q0 + lq) * EDIM + half * 8;
    const bf16x8 qf0h = *(const bf16x8*)(qh_hi + qoff);
    const bf16x8 qf1h = *(const bf16x8*)(qh_hi + qoff + 16);
    const bf16x8 qf2h = *(const bf16x8*)(qh_hi + qoff + 32);
    const bf16x8 qf0l = *(const bf16x8*)(qh_lo + qoff);
    const bf16x8 qf1l = *(const bf16x8*)(qh_lo + qoff + 16);
    const bf16x8 qf2l = *(const bf16x8*)(qh_lo + qoff + 32);

    const size_t koff = ((size_t)bh * NSEQ + lq) * EDIM + half * 8;
    const size_t voff = ((size_t)bh * 64 + lq) * NSEQ + half * 8;

    f32x16 acc0 = {}, acc1 = {};
    float m = -INFINITY, lsum = 0.0f;

    for (int kv0 = 0; kv0 < NSEQ; kv0 += 32) {
        // K A-fragments: row kv = kv0+lq, e = 16*i + 8*half + j
        const size_t kc = koff + (size_t)kv0 * EDIM;
        const bf16x8 kf0h = *(const bf16x8*)(kh_hi + kc);
        const bf16x8 kf1h = *(const bf16x8*)(kh_hi + kc + 16);
        const bf16x8 kf2h = *(const bf16x8*)(kh_hi + kc + 32);
        const bf16x8 kf0l = *(const bf16x8*)(kh_lo + kc);
        const bf16x8 kf1l = *(const bf16x8*)(kh_lo + kc + 16);
        const bf16x8 kf2l = *(const bf16x8*)(kh_lo + kc + 32);
        // V B-fragments: e-col = 32*t + lq, kv = kv0 + 16*i + 8*half + j
        const bf16x8 vf00h = *(const bf16x8*)(vt_hi + voff + kv0);
        const bf16x8 vf01h = *(const bf16x8*)(vt_hi + voff + kv0 + 16);
        const bf16x8 vf10h = *(const bf16x8*)(vt_hi + voff + (size_t)32 * NSEQ + kv0);
        const bf16x8 vf11h = *(const bf16x8*)(vt_hi + voff + (size_t)32 * NSEQ + kv0 + 16);
        const bf16x8 vf00l = *(const bf16x8*)(vt_lo + voff + kv0);
        const bf16x8 vf01l = *(const bf16x8*)(vt_lo + voff + kv0 + 16);
        const bf16x8 vf10l = *(const bf16x8*)(vt_lo + voff + (size_t)32 * NSEQ + kv0);
        const bf16x8 vf11l = *(const bf16x8*)(vt_lo + voff + (size_t)32 * NSEQ + kv0 + 16);

        f32x16 s = {};
        s = __builtin_amdgcn_mfma_f32_32x32x16_bf16(kf0h, qf0h, s, 0, 0, 0);
        s = __builtin_amdgcn_mfma_f32_32x32x16_bf16(kf1h, qf1h, s, 0, 0, 0);
        s = __builtin_amdgcn_mfma_f32_32x32x16_bf16(kf2h, qf2h, s, 0, 0, 0);
        s = __builtin_amdgcn_mfma_f32_32x32x16_bf16(kf0h, qf0l, s, 0, 0, 0);
        s = __builtin_amdgcn_mfma_f32_32x32x16_bf16(kf1h, qf1l, s, 0, 0, 0);
        s = __builtin_amdgcn_mfma_f32_32x32x16_bf16(kf2h, qf2l, s, 0, 0, 0);
        s = __builtin_amdgcn_mfma_f32_32x32x16_bf16(kf0l, qf0h, s, 0, 0, 0);
        s = __builtin_amdgcn_mfma_f32_32x32x16_bf16(kf1l, qf1h, s, 0, 0, 0);
        s = __builtin_amdgcn_mfma_f32_32x32x16_bf16(kf2l, qf2h, s, 0, 0, 0);
        // lane holds s for q = lq, kv(r) = (r&3) + 8*(r>>2) + 4*half

        float mx = fmaxf(fmaxf(fmaxf(s[0], s[1]),  fmaxf(s[2],  s[3])),
                         fmaxf(fmaxf(s[4], s[5]),  fmaxf(s[6],  s[7])));
        mx = fmaxf(mx, fmaxf(fmaxf(fmaxf(s[8],  s[9]),  fmaxf(s[10], s[11])),
                             fmaxf(fmaxf(s[12], s[13]), fmaxf(s[14], s[15]))));
        mx = fmaxf(mx, __shfl_xor(mx, 32));

        if (__any(mx > m + 8.0f)) {            // defer-max: rare
            const float mn = fmaxf(m, mx);
            const float al = exp2f(m - mn);    // alpha for q = lq
            m = mn;
            lsum *= al;
            #pragma unroll
            for (int r = 0; r < 16; ++r) {
                const int qr = (r & 3) + 8 * (r >> 2) + 4 * half;
                const float ar = __shfl(al, qr);
                acc0[r] *= ar; acc1[r] *= ar;
            }
        }

        float p[16];
        float ls = 0.0f;
        #pragma unroll
        for (int r = 0; r < 16; ++r) { p[r] = exp2f(s[r] - m); ls += p[r]; }
        lsum += ls;

        // pack P (hi + residual lo) to bf16 pairs; exchange with lane^32
        unsigned int pkh[8], pkl[8], xkh[8], xkl[8];
        #pragma unroll
        for (int j = 0; j < 8; ++j) {
            const unsigned int h = cvt_pk_bf16(p[2*j], p[2*j+1]);
            pkh[j] = h;
            const float r0 = p[2*j]   - __uint_as_float(h << 16);
            const float r1 = p[2*j+1] - __uint_as_float(h & 0xffff0000u);
            pkl[j] = cvt_pk_bf16(r0, r1);
        }
        #pragma unroll
        for (int j = 0; j < 8; ++j) {
            xkh[j] = __shfl_xor(pkh[j], 32);
            xkl[j] = __shfl_xor(pkl[j], 32);
        }

        u32x4 a0h, a1h, a0l, a1l;
        if (half == 0) {
            a0h = (u32x4){pkh[0], pkh[1], xkh[0], xkh[1]};
            a1h = (u32x4){pkh[4], pkh[5], xkh[4], xkh[5]};
            a0l = (u32x4){pkl[0], pkl[1], xkl[0], xkl[1]};
            a1l = (u32x4){pkl[4], pkl[5], xkl[4], xkl[5]};
        } else {
            a0h = (u32x4){xkh[2], xkh[3], pkh[2], pkh[3]};
            a1h = (u32x4){xkh[6], xkh[7], pkh[6], pkh[7]};
            a0l = (u32x4){xkl[2], xkl[3], pkl[2], pkl[3]};
            a1l = (u32x4){xkl[6], xkl[7], pkl[6], pkl[7]};
        }
        const bf16x8 pa0h = __builtin_bit_cast(bf16x8, a0h);  // kv 0-15
        const bf16x8 pa1h = __builtin_bit_cast(bf16x8, a1h);  // kv 16-31
        const bf16x8 pa0l = __builtin_bit_cast(bf16x8, a0l);
        const bf16x8 pa1l = __builtin_bit_cast(bf16x8, a1l);

        acc0 = __builtin_amdgcn_mfma_f32_32x32x16_bf16(pa0h, vf00h, acc0, 0, 0, 0);
        acc0 = __builtin_amdgcn_mfma_f32_32x32x16_bf16(pa1h, vf01h, acc0, 0, 0, 0);
        acc0 = __builtin_amdgcn_mfma_f32_32x32x16_bf16(pa0h, vf00l, acc0, 0, 0, 0);
        acc0 = __builtin_amdgcn_mfma_f32_32x32x16_bf16(pa1h, vf01l, acc0, 0, 0, 0);
        acc0 = __builtin_amdgcn_mfma_f32_32x32x16_bf16(pa0l, vf00h, acc0, 0, 0, 0);
        acc0 = __builtin_amdgcn_mfma_f32_32x32x16_bf16(pa1l, vf01h, acc0, 0, 0, 0);
        acc1 = __builtin_amdgcn_mfma_f32_32x32x16_bf16(pa0h, vf10h, acc1, 0, 0, 0);
        acc1 = __builtin_amdgcn_mfma_f32_32x32x16_bf16(pa1h, vf11h, acc1, 0, 0, 0);
        acc1 = __builtin_amdgcn_mfma_f32_32x32x16_bf16(pa0h, vf10l, acc1, 0, 0, 0);
        acc1 = __builtin_amdgcn_mfma_f32_32x32x16_bf16(pa1h, vf11l, acc1, 0, 0, 0);
        acc1 = __builtin_amdgcn_mfma_f32_32x32x16_bf16(pa0l, vf10h, acc1, 0, 0, 0);
        acc1 = __builtin_amdgcn_mfma_f32_32x32x16_bf16(pa1l, vf11h, acc1, 0, 0, 0);
    }

    lsum += __shfl_xor(lsum, 32);
    const float linv = 1.0f / lsum;            // for q = lq

    float* xp = xb + ((size_t)bh * NSEQ + q0) * EDIM;
    #pragma unroll
    for (int r = 0; r < 16; ++r) {
        const int qr = (r & 3) + 8 * (r >> 2) + 4 * half;
        const float li = __shfl(linv, qr);
        xp[(size_t)qr * EDIM + lq] = acc0[r] * li;
        if (lq < 16) xp[(size_t)qr * EDIM + 32 + lq] = acc1[r] * li;
    }
}

// ---------------------------------------------------------------------------
// Output projection + VN bias-norm: out[b,n,o,c] from xb[b,h,n,e] (f32).
__global__ __launch_bounds__(256) void vn_oproj(
    const float* __restrict__ xb,
    const float* __restrict__ wt,   // Wp^T [CIN][COUT]
    const float* __restrict__ bias,
    float* __restrict__ out)
{
    const int t  = threadIdx.x;
    const int nl = t >> 5;
    const int o0 = (t & 31) << 2;
    const long bn = (long)blockIdx.x * 8 + nl;
    const int b = (int)(bn >> 11);
    const int n = (int)(bn & (NSEQ - 1));
    const float* xbase = xb + ((size_t)b * NH * NSEQ + n) * EDIM;

    float a[4][3] = {};
    for (int i = 0; i < CIN; ++i) {
        const float4 w = *(const float4*)(wt + (size_t)i * COUT + o0);
        const float wv[4] = { w.x, w.y, w.z, w.w };
        const float* xp = xbase + (size_t)(i >> 4) * NSEQ * EDIM + (i & 15) * 3;
        const float xv[3] = { xp[0], xp[1], xp[2] };
        #pragma unroll
        for (int j = 0; j < 4; ++j)
            #pragma unroll
            for (int c = 0; c < 3; ++c)
                a[j][c] = fmaf(wv[j], xv[c], a[j][c]);
    }
    #pragma unroll
    for (int j = 0; j < 4; ++j) {
        const int o = o0 + j;
        const float nrm = sqrtf(a[j][0]*a[j][0] + a[j][1]*a[j][1] + a[j][2]*a[j][2]);
        const float f = 1.0f + bias[o] / (nrm + kBiasEps);
        float* dp = out + ((size_t)bn * COUT + o) * 3;
        dp[0] = a[j][0] * f;
        dp[1] = a[j][1] * f;
        dp[2] = a[j][2] * f;
    }
}

// ---------------------------------------------------------------------------
extern "C" void kernel_launch(void* const* d_in, const int* in_sizes, int n_in,
                              void* d_out, int out_size, void* d_ws, size_t ws_size,
                              hipStream_t stream)
{
    const float* q  = (const float*)d_in[0];
    const float* v  = (const float*)d_in[1];
    const float* Wq = (const float*)d_in[2];
    const float* bq = (const float*)d_in[3];
    const float* Wk = (const float*)d_in[4];
    const float* bk = (const float*)d_in[5];
    const float* Wv = (const float*)d_in[6];
    const float* bv = (const float*)d_in[7];
    const float* Wp = (const float*)d_in[8];
    const float* bp = (const float*)d_in[9];
    float* out = (float*)d_out;
    float* wsf = (float*)d_ws;

    const size_t WT_FLOATS = (size_t)4 * CIN * COUT;               // 65536
    const size_t QKV_ELEMS = (size_t)NB * NH * NSEQ * EDIM;        // 3145728 bf16
    const size_t VT_ELEMS  = (size_t)NB * NH * 64 * NSEQ;          // 4194304 bf16

    float* wt = wsf;
    unsigned short* qh_hi = (unsigned short*)(wsf + WT_FLOATS);
    unsigned short* qh_lo = qh_hi + QKV_ELEMS;
    unsigned short* kh_hi = qh_lo + QKV_ELEMS;
    unsigned short* kh_lo = kh_hi + QKV_ELEMS;
    unsigned short* vt_hi = kh_lo + QKV_ELEMS;
    unsigned short* vt_lo = vt_hi + VT_ELEMS;
    float* xb = (float*)(vt_lo + VT_ELEMS);

    transpose_w<<<dim3(64, 4), 256, 0, stream>>>(Wq, Wk, Wv, Wp, wt);
    vn_proj<<<dim3(NB * NSEQ / 8, 3), 256, 0, stream>>>(
        q, v, wt, bq, bk, bv, qh_hi, qh_lo, kh_hi, kh_lo, vt_hi, vt_lo);
    vn_attn_mfma<<<dim3(NSEQ / 128, NH, NB), 256, 0, stream>>>(
        qh_hi, qh_lo, kh_hi, kh_lo, vt_hi, vt_lo, xb);
    vn_oproj<<<dim3(NB * NSEQ / 8), 256, 0, stream>>>(
        xb, wt + 3 * (size_t)CIN * COUT, bp, out);
}